// Round 1
// baseline (140.880 us; speedup 1.0000x reference)
//
#include <hip/hip_runtime.h>

// RoutingMaskLayer: out[b,h,w,j] = in[b,h,w, argmax(routing[b,:])*RW + j]
// Shapes: in [32,56,56,256] f32, routing [32,4] f32, out [32,56,56,64] f32.
// Pure memory-bound gather; selected channels are a contiguous 256B block per
// pixel, so one float4 per thread gives perfect coalescing on both sides.

#define NB 32
#define NH 56
#define NW 56
#define NC 256
#define NROUTES 4
#define RW (NC / NROUTES)          // 64 channels selected per sample
#define PIX_F4 (RW / 4)            // 16 float4 per output pixel
#define TOTAL_F4 (NB * NH * NW * PIX_F4)  // 1,605,632

__global__ __launch_bounds__(256) void
RoutingMaskLayer_51453708206705_kernel(const float4* __restrict__ in,
                                       const float* __restrict__ routing,
                                       float4* __restrict__ out) {
    int i = blockIdx.x * blockDim.x + threadIdx.x;   // output float4 index
    if (i >= TOTAL_F4) return;

    int pix = i >> 4;          // which (b,h,w) pixel   (PIX_F4 == 16)
    int j4  = i & 15;          // which float4 within the selected 64 channels
    int b   = pix / (NH * NW); // sample index (compiler: magic-mul)

    // argmax over 4 routing logits, first-max tie-break (matches jnp.argmax).
    const float* r = routing + b * NROUTES;
    float r0 = r[0], r1 = r[1], r2 = r[2], r3 = r[3];
    int route = 0; float best = r0;
    if (r1 > best) { best = r1; route = 1; }
    if (r2 > best) { best = r2; route = 2; }
    if (r3 > best) { best = r3; route = 3; }

    // input pixel stride = 256 floats = 64 float4; route block = 16 float4.
    out[i] = in[pix * (NC / 4) + route * PIX_F4 + j4];
}

extern "C" void kernel_launch(void* const* d_in, const int* in_sizes, int n_in,
                              void* d_out, int out_size, void* d_ws, size_t ws_size,
                              hipStream_t stream) {
    const float4* in      = (const float4*)d_in[0];
    const float*  routing = (const float*)d_in[1];
    float4*       out     = (float4*)d_out;

    constexpr int block = 256;
    constexpr int grid  = (TOTAL_F4 + block - 1) / block;  // 6272
    RoutingMaskLayer_51453708206705_kernel<<<grid, block, 0, stream>>>(in, routing, out);
}